// Round 19
// baseline (393.728 us; speedup 1.0000x reference)
//
#include <hip/hip_runtime.h>
#include <hip/hip_fp8.h>

#define N_NODES 500000
#define N_EDGES 8000000
#define N_GRAPHS 8192
#define BKT 512                 // nodes per bucket
#define NBK 977                 // ceil(N_NODES / BKT)
#define C_CAP 9216              // bucket capacity: mean 8188 + ~11 sigma
#define TILE2 8192              // edges per build block
#define NTB2 977                // ceil(N_EDGES / TILE2)
#define CSR_IT 9                // ceil(C_CAP / 1024)

typedef __attribute__((ext_vector_type(2))) float v2f;
typedef __attribute__((ext_vector_type(4))) unsigned v4u;   // native vec for NT store

// ---- fp8 e4m3 <-> f32 (HW path; word-select must be an immediate -> template)
#if __has_builtin(__builtin_amdgcn_cvt_pk_f32_fp8)
template <bool HI>
__device__ __forceinline__ v2f cvt2fp8(unsigned w) {
    return __builtin_amdgcn_cvt_pk_f32_fp8((int)w, HI);
}
#else
template <bool HI>
__device__ __forceinline__ v2f cvt2fp8(unsigned w) {
    unsigned h16 = HI ? (w >> 16) : (w & 0xFFFFu);
    __hip_fp8_e4m3 a, b;
    a.__x = (__hip_fp8_storage_t)(h16 & 0xFFu);
    b.__x = (__hip_fp8_storage_t)(h16 >> 8);
    v2f r; r.x = (float)a; r.y = (float)b; return r;
}
#endif
#if __has_builtin(__builtin_amdgcn_cvt_pk_fp8_f32)
__device__ __forceinline__ unsigned pk4fp8(float a, float b, float c, float d) {
    int r = 0;
    r = __builtin_amdgcn_cvt_pk_fp8_f32(a, b, r, false);
    r = __builtin_amdgcn_cvt_pk_fp8_f32(c, d, r, true);
    return (unsigned)r;
}
#else
__device__ __forceinline__ unsigned pk4fp8(float a, float b, float c, float d) {
    __hip_fp8_e4m3 qa(a), qb(b), qc(c), qd(d);
    return (unsigned)qa.__x | ((unsigned)qb.__x << 8) |
           ((unsigned)qc.__x << 16) | ((unsigned)qd.__x << 24);
}
#endif
__device__ __forceinline__ void addfp8x16(float* acc, uint4 a) {
    v2f p;
    p = cvt2fp8<false>(a.x); acc[0] += p.x; acc[1] += p.y;
    p = cvt2fp8<true>(a.x);  acc[2] += p.x; acc[3] += p.y;
    p = cvt2fp8<false>(a.y); acc[4] += p.x; acc[5] += p.y;
    p = cvt2fp8<true>(a.y);  acc[6] += p.x; acc[7] += p.y;
    p = cvt2fp8<false>(a.z); acc[8] += p.x; acc[9] += p.y;
    p = cvt2fp8<true>(a.z);  acc[10] += p.x; acc[11] += p.y;
    p = cvt2fp8<false>(a.w); acc[12] += p.x; acc[13] += p.y;
    p = cvt2fp8<true>(a.w);  acc[14] += p.x; acc[15] += p.y;
}
__device__ __forceinline__ void addfp8x8(float* acc, uint2 a) {
    v2f p;
    p = cvt2fp8<false>(a.x); acc[0] += p.x; acc[1] += p.y;
    p = cvt2fp8<true>(a.x);  acc[2] += p.x; acc[3] += p.y;
    p = cvt2fp8<false>(a.y); acc[4] += p.x; acc[5] += p.y;
    p = cvt2fp8<true>(a.y);  acc[6] += p.x; acc[7] += p.y;
}

// ---- barrier-light block-exclusive scan for 1024-thread blocks (16 waves):
// in-wave shfl scan (no barriers) + one cross-wave pass; 2 barriers total.
__device__ __forceinline__ int blockscan_excl(int v, int* wsum, int* woff) {
    int t = threadIdx.x;
    int lane = t & 63, wid = t >> 6;
    int inc = v;
#pragma unroll
    for (int o = 1; o <= 32; o <<= 1) {
        int p = __shfl_up(inc, o, 64);
        if (lane >= o) inc += p;
    }
    if (lane == 63) wsum[wid] = inc;
    __syncthreads();
    if (wid == 0) {
        int ws = (lane < 16) ? wsum[lane] : 0;
#pragma unroll
        for (int o = 1; o <= 8; o <<= 1) {
            int p = __shfl_up(ws, o, 64);
            if (lane >= o) ws += p;
        }
        if (lane < 16) woff[lane] = ws - wsum[lane];
    }
    __syncthreads();
    return inc - v + woff[wid];
}

// ---- init: zero pooled+cnt, set gcursor bases ----
__global__ void k_init(float* __restrict__ pooled, int* __restrict__ gcursor) {
    int i = blockIdx.x * 256 + threadIdx.x;
    if (i < N_GRAPHS * 17) pooled[i] = 0.0f;
    if (i < NBK) gcursor[i] = i * C_CAP;
}

// ---- one-pass bucket build with in-LDS reorder -> coalesced packed writes ----
__global__ __launch_bounds__(1024) void
k_build(const int4* __restrict__ row4, const int4* __restrict__ col4,
        int* __restrict__ gcursor, unsigned* __restrict__ packed, int E) {
    __shared__ unsigned sortedv[TILE2];        // 32 KB
    __shared__ unsigned short sortedb[TILE2];  // 16 KB
    __shared__ int hist2[2][1024];             // 8 KB
    __shared__ int lbase[1024];                // 4 KB
    __shared__ int runbase[1024];              // 4 KB
    __shared__ int wsum[16], woff[16];
    __shared__ int stotal;
    int t = threadIdx.x, b = blockIdx.x;
    int sub = t >> 9;
    hist2[0][t] = 0; hist2[1][t] = 0;
    __syncthreads();
    unsigned uval[8];
    unsigned short ub[8];
#pragma unroll
    for (int k = 0; k < 2; k++) {
        int vi = b * 2048 + k * 1024 + t;
        int j0 = k * 4;
        if (vi * 4 < E) {                      // E % 4 == 0: whole int4 valid
            int4 c = col4[vi];
            int4 r = row4[vi];
            unsigned cc, rr;
            cc = (unsigned)c.x; rr = (unsigned)r.x;
            if (cc < N_NODES && rr < N_NODES) { uval[j0] = (rr << 9) | (cc & 511u); ub[j0] = (unsigned short)(cc >> 9); atomicAdd(&hist2[sub][cc >> 9], 1); } else ub[j0] = 0xFFFFu;
            cc = (unsigned)c.y; rr = (unsigned)r.y;
            if (cc < N_NODES && rr < N_NODES) { uval[j0+1] = (rr << 9) | (cc & 511u); ub[j0+1] = (unsigned short)(cc >> 9); atomicAdd(&hist2[sub][cc >> 9], 1); } else ub[j0+1] = 0xFFFFu;
            cc = (unsigned)c.z; rr = (unsigned)r.z;
            if (cc < N_NODES && rr < N_NODES) { uval[j0+2] = (rr << 9) | (cc & 511u); ub[j0+2] = (unsigned short)(cc >> 9); atomicAdd(&hist2[sub][cc >> 9], 1); } else ub[j0+2] = 0xFFFFu;
            cc = (unsigned)c.w; rr = (unsigned)r.w;
            if (cc < N_NODES && rr < N_NODES) { uval[j0+3] = (rr << 9) | (cc & 511u); ub[j0+3] = (unsigned short)(cc >> 9); atomicAdd(&hist2[sub][cc >> 9], 1); } else ub[j0+3] = 0xFFFFu;
        } else {
            ub[j0] = 0xFFFFu; ub[j0+1] = 0xFFFFu; ub[j0+2] = 0xFFFFu; ub[j0+3] = 0xFFFFu;
        }
    }
    __syncthreads();
    int tot = (t < NBK) ? (hist2[0][t] + hist2[1][t]) : 0;
    int excl = blockscan_excl(tot, wsum, woff);
    lbase[t] = excl;
    if (t == 1023) stotal = excl + tot;   // tot==0 here; excl = grand total
    if (t < NBK && tot) runbase[t] = atomicAdd(&gcursor[t], tot);
    hist2[0][t] = 0;                // reuse as scatter cursor
    __syncthreads();
    int total = stotal;
#pragma unroll
    for (int j = 0; j < 8; j++) {
        unsigned bb = ub[j];
        if (bb != 0xFFFFu) {
            int l = lbase[bb] + atomicAdd(&hist2[0][bb], 1);
            sortedv[l] = uval[j];
            sortedb[l] = (unsigned short)bb;
        }
    }
    __syncthreads();
    for (int l = t; l < total; l += 1024) {
        int bb = sortedb[l];
        packed[runbase[bb] + (l - lbase[bb])] = sortedv[l];
    }
}

// ---- bucket sizes -> exclusive offsets goff[NBK+1] (single block) ----
__global__ __launch_bounds__(1024) void
k_goff(const int* __restrict__ gcursor, int* __restrict__ goff) {
    __shared__ int wsum[16], woff[16];
    int t = threadIdx.x;
    int v = (t < NBK) ? (gcursor[t] - t * C_CAP) : 0;
    int excl = blockscan_excl(v, wsum, woff);
    if (t < NBK) goff[t] = excl;
    if (t == NBK) goff[NBK] = excl;   // v==0 here; excl = grand total
}

// ---- per-bucket packed -> compact CSR + rowptr + dinv + FUSED layer-1(fp8) ----
__global__ __launch_bounds__(1024) void
k_csr(const unsigned* __restrict__ packed, const int* __restrict__ goff,
      const float* __restrict__ x, const float* __restrict__ W1,
      int* __restrict__ srcs, int* __restrict__ rowptr,
      float* __restrict__ dinv_g, uint4* __restrict__ hsu, int N) {
    __shared__ int sortedv[C_CAP];  // 36 KB
    __shared__ int hist2[2][BKT];   // 4 KB
    __shared__ int off[BKT];        // 2 KB
    __shared__ int wsum[16], woff[16];
    __shared__ float sW1[144];
    int t = threadIdx.x, b = blockIdx.x;
    int h = t >> 9;
    if (t < 144) sW1[t] = W1[t];
    ((int*)hist2)[t] = 0;
    __syncthreads();
    int gbase = goff[b];
    int cnt = goff[b + 1] - gbase;
    int sfix = b * C_CAP;
    unsigned pw[CSR_IT];
#pragma unroll
    for (int k = 0; k < CSR_IT; k++) {
        int i = k * 1024 + t;
        if (i < cnt) {
            unsigned w = packed[sfix + i];
            pw[k] = w;
            atomicAdd(&hist2[h][w & 511u], 1);
        } else pw[k] = 0xFFFFFFFFu;
    }
    __syncthreads();
    int ls = (t < BKT) ? (hist2[0][t] + hist2[1][t]) : 0;
    int excl = blockscan_excl(ls, wsum, woff);
    int v = b * BKT + t;
    float di = rsqrtf(1.0f + (float)ls);
    if (t < BKT) {
        off[t] = excl;
        if (v < N) {
            rowptr[v] = gbase + excl;
            dinv_g[v] = di;
        }
    }
    if (b == NBK - 1 && t == 0) rowptr[N] = gbase + cnt;
    __syncthreads();
    if (t < BKT) hist2[0][t] = 0;
    __syncthreads();
#pragma unroll
    for (int k = 0; k < CSR_IT; k++) {
        unsigned w = pw[k];
        if (w != 0xFFFFFFFFu) {
            unsigned c = w & 511u;
            int l = off[c] + atomicAdd(&hist2[0][c], 1);
            sortedv[l] = (int)(w >> 9);
        }
    }
    __syncthreads();
    for (int l = t; l < cnt; l += 1024)
        __builtin_nontemporal_store(sortedv[l], &srcs[gbase + l]);
    // ---- fused layer-1: hs(fp8 e4m3) = (x @ W1) * dinv for this bucket ----
    if (t < BKT && v < N) {
        float xi[9];
#pragma unroll
        for (int k = 0; k < 9; k++) xi[k] = x[v * 9 + k];
        float hh[16];
#pragma unroll
        for (int j = 0; j < 16; j++) {
            float acc = 0.f;
#pragma unroll
            for (int k = 0; k < 9; k++) acc += xi[k] * sW1[k * 16 + j];
            hh[j] = acc * di;
        }
        uint4 w;
        w.x = pk4fp8(hh[0], hh[1], hh[2], hh[3]);
        w.y = pk4fp8(hh[4], hh[5], hh[6], hh[7]);
        w.z = pk4fp8(hh[8], hh[9], hh[10], hh[11]);
        w.w = pk4fp8(hh[12], hh[13], hh[14], hh[15]);
        hsu[v] = w;
    }
}

// ---- pull layer 1 (fp8, 1 lane/node) + fused layer-2 node transform ----
__global__ void k_pullA(const int* __restrict__ rowptr, const int* __restrict__ srcs,
                        const uint4* __restrict__ hsu, const float* __restrict__ dinv,
                        const float* __restrict__ b1, const float* __restrict__ W2,
                        uint4* __restrict__ hs2u, int N) {
    int v = blockIdx.x * 256 + threadIdx.x;
    if (v >= N) return;
    int s = rowptr[v], e = rowptr[v + 1];
    float acc[16];
    {
        uint4 u = hsu[v];   // self loop
#pragma unroll
        for (int i = 0; i < 16; i++) acc[i] = 0.f;
        addfp8x16(acc, u);
    }
    int k = s;
    for (; k + 4 <= e; k += 4) {
        int r0 = __builtin_nontemporal_load(&srcs[k]);
        int r1 = __builtin_nontemporal_load(&srcs[k + 1]);
        int r2 = __builtin_nontemporal_load(&srcs[k + 2]);
        int r3 = __builtin_nontemporal_load(&srcs[k + 3]);
        uint4 a0 = hsu[r0];
        uint4 a1 = hsu[r1];
        uint4 a2 = hsu[r2];
        uint4 a3 = hsu[r3];
        addfp8x16(acc, a0); addfp8x16(acc, a1);
        addfp8x16(acc, a2); addfp8x16(acc, a3);
    }
    for (; k < e; k++) addfp8x16(acc, hsu[__builtin_nontemporal_load(&srcs[k])]);
    float di = dinv[v];
    float h1[16];
#pragma unroll
    for (int i = 0; i < 16; i++) {
        float tt = acc[i] * di + b1[i];
        h1[i] = tt > 0.f ? tt : 0.f;
    }
    float o[16];
#pragma unroll
    for (int i = 0; i < 16; i++) o[i] = 0.f;
#pragma unroll
    for (int kk = 0; kk < 16; kk++) {
#pragma unroll
        for (int i = 0; i < 16; i++) o[i] += h1[kk] * W2[kk * 16 + i];
    }
    v4u w;
    w.x = pk4fp8(o[0] * di, o[1] * di, o[2] * di, o[3] * di);
    w.y = pk4fp8(o[4] * di, o[5] * di, o[6] * di, o[7] * di);
    w.z = pk4fp8(o[8] * di, o[9] * di, o[10] * di, o[11] * di);
    w.w = pk4fp8(o[12] * di, o[13] * di, o[14] * di, o[15] * di);
    __builtin_nontemporal_store(w, (v4u*)&hs2u[v]);
}

// ---- pull layer 2 (fp8, 2 lanes/node) + fused h2 transform + fused pool ----
// NOTE: N*2 = 1,000,000 is a multiple of 64 -> exiting waves are homogeneous.
__global__ void k_pullB(const int* __restrict__ rowptr, const int* __restrict__ srcs,
                        const uint2* __restrict__ hs2u, const float* __restrict__ dinv,
                        const float* __restrict__ b2, const int* __restrict__ batch,
                        float* __restrict__ pooled, float* __restrict__ cnt, int N) {
    int tid = blockIdx.x * 256 + threadIdx.x;
    int v = tid >> 1;
    int q = tid & 1;
    if (v >= N) return;
    int s = rowptr[v], e = rowptr[v + 1];
    float acc[8];
#pragma unroll
    for (int i = 0; i < 8; i++) acc[i] = 0.f;
    addfp8x8(acc, hs2u[v * 2 + q]);   // self loop
    int k = s;
    for (; k + 8 <= e; k += 8) {
        int r0 = __builtin_nontemporal_load(&srcs[k]);
        int r1 = __builtin_nontemporal_load(&srcs[k + 1]);
        int r2 = __builtin_nontemporal_load(&srcs[k + 2]);
        int r3 = __builtin_nontemporal_load(&srcs[k + 3]);
        int r4 = __builtin_nontemporal_load(&srcs[k + 4]);
        int r5 = __builtin_nontemporal_load(&srcs[k + 5]);
        int r6 = __builtin_nontemporal_load(&srcs[k + 6]);
        int r7 = __builtin_nontemporal_load(&srcs[k + 7]);
        uint2 a0 = hs2u[r0 * 2 + q];
        uint2 a1 = hs2u[r1 * 2 + q];
        uint2 a2 = hs2u[r2 * 2 + q];
        uint2 a3 = hs2u[r3 * 2 + q];
        uint2 a4 = hs2u[r4 * 2 + q];
        uint2 a5 = hs2u[r5 * 2 + q];
        uint2 a6 = hs2u[r6 * 2 + q];
        uint2 a7 = hs2u[r7 * 2 + q];
        addfp8x8(acc, a0); addfp8x8(acc, a1); addfp8x8(acc, a2); addfp8x8(acc, a3);
        addfp8x8(acc, a4); addfp8x8(acc, a5); addfp8x8(acc, a6); addfp8x8(acc, a7);
    }
    for (; k + 4 <= e; k += 4) {
        int r0 = __builtin_nontemporal_load(&srcs[k]);
        int r1 = __builtin_nontemporal_load(&srcs[k + 1]);
        int r2 = __builtin_nontemporal_load(&srcs[k + 2]);
        int r3 = __builtin_nontemporal_load(&srcs[k + 3]);
        uint2 a0 = hs2u[r0 * 2 + q];
        uint2 a1 = hs2u[r1 * 2 + q];
        uint2 a2 = hs2u[r2 * 2 + q];
        uint2 a3 = hs2u[r3 * 2 + q];
        addfp8x8(acc, a0); addfp8x8(acc, a1); addfp8x8(acc, a2); addfp8x8(acc, a3);
    }
    for (; k < e; k++) addfp8x8(acc, hs2u[__builtin_nontemporal_load(&srcs[k]) * 2 + q]);
    float di = dinv[v];
    float h2[8];
#pragma unroll
    for (int i = 0; i < 8; i++) {
        float tt = acc[i] * di + b2[q * 8 + i];
        h2[i] = tt > 0.f ? tt : 0.f;
    }
    // ---- fused pool: guarded inclusive segmented scan over node dim ----
    int l = threadIdx.x & 63;
    int g = batch[v];
    float c = (q == 0) ? 1.0f : 0.0f;
#pragma unroll
    for (int off = 2; off <= 32; off <<= 1) {
        int pg = __shfl_up(g, off, 64);
        float pc = __shfl_up(c, off, 64);
        float p0 = __shfl_up(h2[0], off, 64);
        float p1 = __shfl_up(h2[1], off, 64);
        float p2 = __shfl_up(h2[2], off, 64);
        float p3 = __shfl_up(h2[3], off, 64);
        float p4 = __shfl_up(h2[4], off, 64);
        float p5 = __shfl_up(h2[5], off, 64);
        float p6 = __shfl_up(h2[6], off, 64);
        float p7 = __shfl_up(h2[7], off, 64);
        if (l >= off && pg == g) {
            c += pc;
            h2[0] += p0; h2[1] += p1; h2[2] += p2; h2[3] += p3;
            h2[4] += p4; h2[5] += p5; h2[6] += p6; h2[7] += p7;
        }
    }
    int gn = __shfl_down(g, 2, 64);
    bool tail = (l >= 62) || (gn != g);
    if (tail) {
#pragma unroll
        for (int i = 0; i < 8; i++)
            atomicAdd(&pooled[g * 16 + q * 8 + i], h2[i]);
        if (q == 0) atomicAdd(&cnt[g], c);
    }
}

// ---- head MLP ----
__global__ void k_head(const float* __restrict__ pooled, const float* __restrict__ cnt,
                       const float* __restrict__ meta, const float* __restrict__ Wh1,
                       const float* __restrict__ bh1, const float* __restrict__ Wh2,
                       const float* __restrict__ bh2, float* __restrict__ out, int G) {
    int g = blockIdx.x * 256 + threadIdx.x;
    if (g >= G) return;
    float z[43];
    float c = cnt[g];
    c = c > 1.f ? c : 1.f;
#pragma unroll
    for (int j = 0; j < 16; j++) z[j] = pooled[g * 16 + j] / c;
#pragma unroll
    for (int j = 0; j < 27; j++) z[16 + j] = meta[g * 27 + j];
    float acc2 = bh2[0];
#pragma unroll
    for (int jj = 0; jj < 16; jj++) {
        float a = bh1[jj];
#pragma unroll
        for (int k = 0; k < 43; k++) a += z[k] * Wh1[k * 16 + jj];
        a = a > 0.f ? a : 0.f;
        acc2 += a * Wh2[jj];
    }
    out[g] = acc2;
}

extern "C" void kernel_launch(void* const* d_in, const int* in_sizes, int n_in,
                              void* d_out, int out_size, void* d_ws, size_t ws_size,
                              hipStream_t stream) {
    const float* x    = (const float*)d_in[0];
    const int*   ei   = (const int*)d_in[1];   // [2, E]: row then col
    const int*   batch= (const int*)d_in[2];
    const float* meta = (const float*)d_in[3];
    const float* W1   = (const float*)d_in[4];
    const float* b1   = (const float*)d_in[5];
    const float* W2   = (const float*)d_in[6];
    const float* b2   = (const float*)d_in[7];
    const float* Wh1  = (const float*)d_in[8];
    const float* bh1  = (const float*)d_in[9];
    const float* Wh2  = (const float*)d_in[10];
    const float* bh2  = (const float*)d_in[11];
    float* out = (float*)d_out;

    const int N = N_NODES, E = N_EDGES, G = N_GRAPHS;
    const int* row = ei;
    const int* col = ei + E;

    // workspace layout (4-byte units), ~84.6 MB total (no aliasing).
    float*    ws      = (float*)d_ws;
    float*    dinv    = ws;                          // 512,000
    unsigned* packed  = (unsigned*)(ws + 512000);    // 9,004,032
    int*      srcs    = (int*)(packed + 9004032);    // 8,000,000
    unsigned* hsu     = (unsigned*)(srcs + 8000000); // 2,000,000 (fp8, 16B/node)
    unsigned* hs2u    = hsu + 2000000;               // 2,000,000 (fp8, 16B/node)
    float*    pooled  = (float*)(hs2u + 2000000);    // 131,072
    float*    cnt     = pooled + G * 16;             // 8,192
    int*      gcursor = (int*)(cnt + G);             // 1,024
    int*      goff    = gcursor + 1024;              // 1,024
    int*      rowptr  = goff + 1024;                 // 500,001

    dim3 blk(256);

    // ---- one-pass bucket build + CSR (+fused fp8 l1) ----
    k_init<<<(G * 17 + 255) / 256, blk, 0, stream>>>(pooled, gcursor);
    k_build<<<NTB2, dim3(1024), 0, stream>>>((const int4*)row, (const int4*)col,
                                             gcursor, packed, E);
    k_goff<<<1, dim3(1024), 0, stream>>>(gcursor, goff);
    k_csr<<<NBK, dim3(1024), 0, stream>>>(packed, goff, x, W1,
                                          srcs, rowptr, dinv, (uint4*)hsu, N);

    // ---- layer 1 aggregation (fp8 gather, 1 lane/node) ----
    k_pullA<<<(N + 255) / 256, blk, 0, stream>>>(rowptr, srcs, (const uint4*)hsu,
                                                 dinv, b1, W2, (uint4*)hs2u, N);

    // ---- layer 2 aggregation (fp8) + fused transform + fused pool ----
    int gP2 = (N * 2 + 255) / 256;
    k_pullB<<<gP2, blk, 0, stream>>>(rowptr, srcs, (const uint2*)hs2u, dinv,
                                     b2, batch, pooled, cnt, N);

    // ---- head ----
    k_head<<<(G + 255) / 256, blk, 0, stream>>>(pooled, cnt, meta, Wh1, bh1, Wh2, bh2, out, G);
}

// Round 20
// 384.565 us; speedup vs baseline: 1.0238x; 1.0238x over previous
//
#include <hip/hip_runtime.h>
#include <hip/hip_fp8.h>

#define N_NODES 500000
#define N_EDGES 8000000
#define N_GRAPHS 8192
#define BKT 512                 // nodes per bucket
#define NBK 977                 // ceil(N_NODES / BKT)
#define C_CAP 9216              // bucket capacity: mean 8188 + ~11 sigma
#define TILE2 8192              // edges per build block
#define NTB2 977                // ceil(N_EDGES / TILE2)
#define CSR_IT 9                // ceil(C_CAP / 1024)
#define HALF_N 250000           // source-half split (4 MB of fp8 features)

typedef __attribute__((ext_vector_type(2))) float v2f;

// ---- fp8 e4m3 <-> f32 (HW path; word-select must be an immediate -> template)
#if __has_builtin(__builtin_amdgcn_cvt_pk_f32_fp8)
template <bool HI>
__device__ __forceinline__ v2f cvt2fp8(unsigned w) {
    return __builtin_amdgcn_cvt_pk_f32_fp8((int)w, HI);
}
#else
template <bool HI>
__device__ __forceinline__ v2f cvt2fp8(unsigned w) {
    unsigned h16 = HI ? (w >> 16) : (w & 0xFFFFu);
    __hip_fp8_e4m3 a, b;
    a.__x = (__hip_fp8_storage_t)(h16 & 0xFFu);
    b.__x = (__hip_fp8_storage_t)(h16 >> 8);
    v2f r; r.x = (float)a; r.y = (float)b; return r;
}
#endif
#if __has_builtin(__builtin_amdgcn_cvt_pk_fp8_f32)
__device__ __forceinline__ unsigned pk4fp8(float a, float b, float c, float d) {
    int r = 0;
    r = __builtin_amdgcn_cvt_pk_fp8_f32(a, b, r, false);
    r = __builtin_amdgcn_cvt_pk_fp8_f32(c, d, r, true);
    return (unsigned)r;
}
#else
__device__ __forceinline__ unsigned pk4fp8(float a, float b, float c, float d) {
    __hip_fp8_e4m3 qa(a), qb(b), qc(c), qd(d);
    return (unsigned)qa.__x | ((unsigned)qb.__x << 8) |
           ((unsigned)qc.__x << 16) | ((unsigned)qd.__x << 24);
}
#endif
__device__ __forceinline__ void addfp8x16(float* acc, uint4 a) {
    v2f p;
    p = cvt2fp8<false>(a.x); acc[0] += p.x; acc[1] += p.y;
    p = cvt2fp8<true>(a.x);  acc[2] += p.x; acc[3] += p.y;
    p = cvt2fp8<false>(a.y); acc[4] += p.x; acc[5] += p.y;
    p = cvt2fp8<true>(a.y);  acc[6] += p.x; acc[7] += p.y;
    p = cvt2fp8<false>(a.z); acc[8] += p.x; acc[9] += p.y;
    p = cvt2fp8<true>(a.z);  acc[10] += p.x; acc[11] += p.y;
    p = cvt2fp8<false>(a.w); acc[12] += p.x; acc[13] += p.y;
    p = cvt2fp8<true>(a.w);  acc[14] += p.x; acc[15] += p.y;
}
__device__ __forceinline__ void addfp8x8(float* acc, uint2 a) {
    v2f p;
    p = cvt2fp8<false>(a.x); acc[0] += p.x; acc[1] += p.y;
    p = cvt2fp8<true>(a.x);  acc[2] += p.x; acc[3] += p.y;
    p = cvt2fp8<false>(a.y); acc[4] += p.x; acc[5] += p.y;
    p = cvt2fp8<true>(a.y);  acc[6] += p.x; acc[7] += p.y;
}

// ---- barrier-light block-exclusive scan for 1024-thread blocks ----
__device__ __forceinline__ int blockscan_excl(int v, int* wsum, int* woff) {
    int t = threadIdx.x;
    int lane = t & 63, wid = t >> 6;
    int inc = v;
#pragma unroll
    for (int o = 1; o <= 32; o <<= 1) {
        int p = __shfl_up(inc, o, 64);
        if (lane >= o) inc += p;
    }
    if (lane == 63) wsum[wid] = inc;
    __syncthreads();
    if (wid == 0) {
        int ws = (lane < 16) ? wsum[lane] : 0;
#pragma unroll
        for (int o = 1; o <= 8; o <<= 1) {
            int p = __shfl_up(ws, o, 64);
            if (lane >= o) ws += p;
        }
        if (lane < 16) woff[lane] = ws - wsum[lane];
    }
    __syncthreads();
    return inc - v + woff[wid];
}

// ---- init: zero pooled+cnt, set gcursor bases ----
__global__ void k_init(float* __restrict__ pooled, int* __restrict__ gcursor) {
    int i = blockIdx.x * 256 + threadIdx.x;
    if (i < N_GRAPHS * 17) pooled[i] = 0.0f;
    if (i < NBK) gcursor[i] = i * C_CAP;
}

// ---- one-pass bucket build with in-LDS reorder -> coalesced packed writes ----
__global__ __launch_bounds__(1024) void
k_build(const int4* __restrict__ row4, const int4* __restrict__ col4,
        int* __restrict__ gcursor, unsigned* __restrict__ packed, int E) {
    __shared__ unsigned sortedv[TILE2];        // 32 KB
    __shared__ unsigned short sortedb[TILE2];  // 16 KB
    __shared__ int hist2[2][1024];             // 8 KB
    __shared__ int lbase[1024];                // 4 KB
    __shared__ int runbase[1024];              // 4 KB
    __shared__ int wsum[16], woff[16];
    __shared__ int stotal;
    int t = threadIdx.x, b = blockIdx.x;
    int sub = t >> 9;
    hist2[0][t] = 0; hist2[1][t] = 0;
    __syncthreads();
    unsigned uval[8];
    unsigned short ub[8];
#pragma unroll
    for (int k = 0; k < 2; k++) {
        int vi = b * 2048 + k * 1024 + t;
        int j0 = k * 4;
        if (vi * 4 < E) {                      // E % 4 == 0: whole int4 valid
            int4 c = col4[vi];
            int4 r = row4[vi];
            unsigned cc, rr;
            cc = (unsigned)c.x; rr = (unsigned)r.x;
            if (cc < N_NODES && rr < N_NODES) { uval[j0] = (rr << 9) | (cc & 511u); ub[j0] = (unsigned short)(cc >> 9); atomicAdd(&hist2[sub][cc >> 9], 1); } else ub[j0] = 0xFFFFu;
            cc = (unsigned)c.y; rr = (unsigned)r.y;
            if (cc < N_NODES && rr < N_NODES) { uval[j0+1] = (rr << 9) | (cc & 511u); ub[j0+1] = (unsigned short)(cc >> 9); atomicAdd(&hist2[sub][cc >> 9], 1); } else ub[j0+1] = 0xFFFFu;
            cc = (unsigned)c.z; rr = (unsigned)r.z;
            if (cc < N_NODES && rr < N_NODES) { uval[j0+2] = (rr << 9) | (cc & 511u); ub[j0+2] = (unsigned short)(cc >> 9); atomicAdd(&hist2[sub][cc >> 9], 1); } else ub[j0+2] = 0xFFFFu;
            cc = (unsigned)c.w; rr = (unsigned)r.w;
            if (cc < N_NODES && rr < N_NODES) { uval[j0+3] = (rr << 9) | (cc & 511u); ub[j0+3] = (unsigned short)(cc >> 9); atomicAdd(&hist2[sub][cc >> 9], 1); } else ub[j0+3] = 0xFFFFu;
        } else {
            ub[j0] = 0xFFFFu; ub[j0+1] = 0xFFFFu; ub[j0+2] = 0xFFFFu; ub[j0+3] = 0xFFFFu;
        }
    }
    __syncthreads();
    int tot = (t < NBK) ? (hist2[0][t] + hist2[1][t]) : 0;
    int excl = blockscan_excl(tot, wsum, woff);
    lbase[t] = excl;
    if (t == 1023) stotal = excl + tot;   // tot==0 here; excl = grand total
    if (t < NBK && tot) runbase[t] = atomicAdd(&gcursor[t], tot);
    hist2[0][t] = 0;                // reuse as scatter cursor
    __syncthreads();
    int total = stotal;
#pragma unroll
    for (int j = 0; j < 8; j++) {
        unsigned bb = ub[j];
        if (bb != 0xFFFFu) {
            int l = lbase[bb] + atomicAdd(&hist2[0][bb], 1);
            sortedv[l] = uval[j];
            sortedb[l] = (unsigned short)bb;
        }
    }
    __syncthreads();
    for (int l = t; l < total; l += 1024) {
        int bb = sortedb[l];
        packed[runbase[bb] + (l - lbase[bb])] = sortedv[l];
    }
}

// ---- bucket sizes -> exclusive offsets goff[NBK+1] (single block) ----
__global__ __launch_bounds__(1024) void
k_goff(const int* __restrict__ gcursor, int* __restrict__ goff) {
    __shared__ int wsum[16], woff[16];
    int t = threadIdx.x;
    int v = (t < NBK) ? (gcursor[t] - t * C_CAP) : 0;
    int excl = blockscan_excl(v, wsum, woff);
    if (t < NBK) goff[t] = excl;
    if (t == NBK) goff[NBK] = excl;   // v==0 here; excl = grand total
}

// ---- per-bucket packed -> compact CSR + rowptr + dinv + FUSED layer-1(fp8) ----
// Sort key = (c_local << 1) | (src >= HALF_N): each node's edge run lists
// low-half sources first -> pulls sweep a 4MB (L2-sized) region per phase.
__global__ __launch_bounds__(1024) void
k_csr(const unsigned* __restrict__ packed, const int* __restrict__ goff,
      const float* __restrict__ x, const float* __restrict__ W1,
      int* __restrict__ srcs, int* __restrict__ rowptr,
      float* __restrict__ dinv_g, uint4* __restrict__ hsu, int N) {
    __shared__ int sortedv[C_CAP];  // 36 KB
    __shared__ int hist2[2][1024];  // 8 KB  (1024 keys)
    __shared__ int off[1024];       // 4 KB
    __shared__ int wsum[16], woff[16];
    __shared__ float sW1[144];
    int t = threadIdx.x, b = blockIdx.x;
    int h = t >> 9;
    if (t < 144) sW1[t] = W1[t];
    hist2[0][t] = 0; hist2[1][t] = 0;
    __syncthreads();
    int gbase = goff[b];
    int cnt = goff[b + 1] - gbase;
    int sfix = b * C_CAP;
    unsigned pw[CSR_IT];
#pragma unroll
    for (int k = 0; k < CSR_IT; k++) {
        int i = k * 1024 + t;
        if (i < cnt) {
            unsigned w = packed[sfix + i];
            pw[k] = w;
            unsigned key = ((w & 511u) << 1) | (unsigned)((w >> 9) >= HALF_N);
            atomicAdd(&hist2[h][key], 1);
        } else pw[k] = 0xFFFFFFFFu;
    }
    __syncthreads();
    int lk = hist2[0][t] + hist2[1][t];       // count of key t
    int excl = blockscan_excl(lk, wsum, woff);
    off[t] = excl;
    __syncthreads();
    int v = b * BKT + (t >> 1);               // dummy for t odd
    if ((t & 1) == 0) {
        int node = t >> 1;
        int vv = b * BKT + node;
        int ls0 = hist2[0][t] + hist2[1][t];
        int ls1 = hist2[0][t + 1] + hist2[1][t + 1];
        int tot = ls0 + ls1;
        if (vv < N) {
            rowptr[vv] = gbase + off[t];
            dinv_g[vv] = rsqrtf(1.0f + (float)tot);
        }
    }
    if (b == NBK - 1 && t == 0) rowptr[N] = gbase + cnt;
    __syncthreads();
    hist2[0][t] = 0;                // reuse as per-key cursor
    __syncthreads();
#pragma unroll
    for (int k = 0; k < CSR_IT; k++) {
        unsigned w = pw[k];
        if (w != 0xFFFFFFFFu) {
            unsigned key = ((w & 511u) << 1) | (unsigned)((w >> 9) >= HALF_N);
            int l = off[key] + atomicAdd(&hist2[0][key], 1);
            sortedv[l] = (int)(w >> 9);
        }
    }
    __syncthreads();
    for (int l = t; l < cnt; l += 1024) srcs[gbase + l] = sortedv[l];
    // ---- fused layer-1: hs(fp8 e4m3) = (x @ W1) * dinv for this bucket ----
    if (t < BKT) {
        int vv = b * BKT + t;
        if (vv < N) {
            int ls0 = hist2[1][t * 2] ? 0 : 0;   // (placeholder, not used)
            float di = dinv_g[vv];
            float xi[9];
#pragma unroll
            for (int k = 0; k < 9; k++) xi[k] = x[vv * 9 + k];
            float hh[16];
#pragma unroll
            for (int j = 0; j < 16; j++) {
                float acc = 0.f;
#pragma unroll
                for (int k = 0; k < 9; k++) acc += xi[k] * sW1[k * 16 + j];
                hh[j] = acc * di;
            }
            uint4 w;
            w.x = pk4fp8(hh[0], hh[1], hh[2], hh[3]);
            w.y = pk4fp8(hh[4], hh[5], hh[6], hh[7]);
            w.z = pk4fp8(hh[8], hh[9], hh[10], hh[11]);
            w.w = pk4fp8(hh[12], hh[13], hh[14], hh[15]);
            hsu[vv] = w;
        }
    }
}

// ---- pull layer 1 (fp8, 1 lane/node) + fused layer-2 node transform ----
__global__ void k_pullA(const int* __restrict__ rowptr, const int* __restrict__ srcs,
                        const uint4* __restrict__ hsu, const float* __restrict__ dinv,
                        const float* __restrict__ b1, const float* __restrict__ W2,
                        uint4* __restrict__ hs2u, int N) {
    int v = blockIdx.x * 256 + threadIdx.x;
    if (v >= N) return;
    int s = rowptr[v], e = rowptr[v + 1];
    float acc[16];
    {
        uint4 u = hsu[v];   // self loop
#pragma unroll
        for (int i = 0; i < 16; i++) acc[i] = 0.f;
        addfp8x16(acc, u);
    }
    int k = s;
    for (; k + 4 <= e; k += 4) {
        int r0 = __builtin_nontemporal_load(&srcs[k]);
        int r1 = __builtin_nontemporal_load(&srcs[k + 1]);
        int r2 = __builtin_nontemporal_load(&srcs[k + 2]);
        int r3 = __builtin_nontemporal_load(&srcs[k + 3]);
        uint4 a0 = hsu[r0];
        uint4 a1 = hsu[r1];
        uint4 a2 = hsu[r2];
        uint4 a3 = hsu[r3];
        addfp8x16(acc, a0); addfp8x16(acc, a1);
        addfp8x16(acc, a2); addfp8x16(acc, a3);
    }
    for (; k < e; k++) addfp8x16(acc, hsu[__builtin_nontemporal_load(&srcs[k])]);
    float di = dinv[v];
    float h1[16];
#pragma unroll
    for (int i = 0; i < 16; i++) {
        float tt = acc[i] * di + b1[i];
        h1[i] = tt > 0.f ? tt : 0.f;
    }
    float o[16];
#pragma unroll
    for (int i = 0; i < 16; i++) o[i] = 0.f;
#pragma unroll
    for (int kk = 0; kk < 16; kk++) {
#pragma unroll
        for (int i = 0; i < 16; i++) o[i] += h1[kk] * W2[kk * 16 + i];
    }
    uint4 w;
    w.x = pk4fp8(o[0] * di, o[1] * di, o[2] * di, o[3] * di);
    w.y = pk4fp8(o[4] * di, o[5] * di, o[6] * di, o[7] * di);
    w.z = pk4fp8(o[8] * di, o[9] * di, o[10] * di, o[11] * di);
    w.w = pk4fp8(o[12] * di, o[13] * di, o[14] * di, o[15] * di);
    hs2u[v] = w;
}

// ---- pull layer 2 (fp8, 2 lanes/node) + fused h2 transform + fused pool ----
// NOTE: N*2 = 1,000,000 is a multiple of 64 -> exiting waves are homogeneous.
__global__ void k_pullB(const int* __restrict__ rowptr, const int* __restrict__ srcs,
                        const uint2* __restrict__ hs2u, const float* __restrict__ dinv,
                        const float* __restrict__ b2, const int* __restrict__ batch,
                        float* __restrict__ pooled, float* __restrict__ cnt, int N) {
    int tid = blockIdx.x * 256 + threadIdx.x;
    int v = tid >> 1;
    int q = tid & 1;
    if (v >= N) return;
    int s = rowptr[v], e = rowptr[v + 1];
    float acc[8];
#pragma unroll
    for (int i = 0; i < 8; i++) acc[i] = 0.f;
    addfp8x8(acc, hs2u[v * 2 + q]);   // self loop
    int k = s;
    for (; k + 8 <= e; k += 8) {
        int r0 = __builtin_nontemporal_load(&srcs[k]);
        int r1 = __builtin_nontemporal_load(&srcs[k + 1]);
        int r2 = __builtin_nontemporal_load(&srcs[k + 2]);
        int r3 = __builtin_nontemporal_load(&srcs[k + 3]);
        int r4 = __builtin_nontemporal_load(&srcs[k + 4]);
        int r5 = __builtin_nontemporal_load(&srcs[k + 5]);
        int r6 = __builtin_nontemporal_load(&srcs[k + 6]);
        int r7 = __builtin_nontemporal_load(&srcs[k + 7]);
        uint2 a0 = hs2u[r0 * 2 + q];
        uint2 a1 = hs2u[r1 * 2 + q];
        uint2 a2 = hs2u[r2 * 2 + q];
        uint2 a3 = hs2u[r3 * 2 + q];
        uint2 a4 = hs2u[r4 * 2 + q];
        uint2 a5 = hs2u[r5 * 2 + q];
        uint2 a6 = hs2u[r6 * 2 + q];
        uint2 a7 = hs2u[r7 * 2 + q];
        addfp8x8(acc, a0); addfp8x8(acc, a1); addfp8x8(acc, a2); addfp8x8(acc, a3);
        addfp8x8(acc, a4); addfp8x8(acc, a5); addfp8x8(acc, a6); addfp8x8(acc, a7);
    }
    for (; k + 4 <= e; k += 4) {
        int r0 = __builtin_nontemporal_load(&srcs[k]);
        int r1 = __builtin_nontemporal_load(&srcs[k + 1]);
        int r2 = __builtin_nontemporal_load(&srcs[k + 2]);
        int r3 = __builtin_nontemporal_load(&srcs[k + 3]);
        uint2 a0 = hs2u[r0 * 2 + q];
        uint2 a1 = hs2u[r1 * 2 + q];
        uint2 a2 = hs2u[r2 * 2 + q];
        uint2 a3 = hs2u[r3 * 2 + q];
        addfp8x8(acc, a0); addfp8x8(acc, a1); addfp8x8(acc, a2); addfp8x8(acc, a3);
    }
    for (; k < e; k++) addfp8x8(acc, hs2u[__builtin_nontemporal_load(&srcs[k]) * 2 + q]);
    float di = dinv[v];
    float h2[8];
#pragma unroll
    for (int i = 0; i < 8; i++) {
        float tt = acc[i] * di + b2[q * 8 + i];
        h2[i] = tt > 0.f ? tt : 0.f;
    }
    // ---- fused pool: guarded inclusive segmented scan over node dim ----
    int l = threadIdx.x & 63;
    int g = batch[v];
    float c = (q == 0) ? 1.0f : 0.0f;
#pragma unroll
    for (int off = 2; off <= 32; off <<= 1) {
        int pg = __shfl_up(g, off, 64);
        float pc = __shfl_up(c, off, 64);
        float p0 = __shfl_up(h2[0], off, 64);
        float p1 = __shfl_up(h2[1], off, 64);
        float p2 = __shfl_up(h2[2], off, 64);
        float p3 = __shfl_up(h2[3], off, 64);
        float p4 = __shfl_up(h2[4], off, 64);
        float p5 = __shfl_up(h2[5], off, 64);
        float p6 = __shfl_up(h2[6], off, 64);
        float p7 = __shfl_up(h2[7], off, 64);
        if (l >= off && pg == g) {
            c += pc;
            h2[0] += p0; h2[1] += p1; h2[2] += p2; h2[3] += p3;
            h2[4] += p4; h2[5] += p5; h2[6] += p6; h2[7] += p7;
        }
    }
    int gn = __shfl_down(g, 2, 64);
    bool tail = (l >= 62) || (gn != g);
    if (tail) {
#pragma unroll
        for (int i = 0; i < 8; i++)
            atomicAdd(&pooled[g * 16 + q * 8 + i], h2[i]);
        if (q == 0) atomicAdd(&cnt[g], c);
    }
}

// ---- head MLP ----
__global__ void k_head(const float* __restrict__ pooled, const float* __restrict__ cnt,
                       const float* __restrict__ meta, const float* __restrict__ Wh1,
                       const float* __restrict__ bh1, const float* __restrict__ Wh2,
                       const float* __restrict__ bh2, float* __restrict__ out, int G) {
    int g = blockIdx.x * 256 + threadIdx.x;
    if (g >= G) return;
    float z[43];
    float c = cnt[g];
    c = c > 1.f ? c : 1.f;
#pragma unroll
    for (int j = 0; j < 16; j++) z[j] = pooled[g * 16 + j] / c;
#pragma unroll
    for (int j = 0; j < 27; j++) z[16 + j] = meta[g * 27 + j];
    float acc2 = bh2[0];
#pragma unroll
    for (int jj = 0; jj < 16; jj++) {
        float a = bh1[jj];
#pragma unroll
        for (int k = 0; k < 43; k++) a += z[k] * Wh1[k * 16 + jj];
        a = a > 0.f ? a : 0.f;
        acc2 += a * Wh2[jj];
    }
    out[g] = acc2;
}

extern "C" void kernel_launch(void* const* d_in, const int* in_sizes, int n_in,
                              void* d_out, int out_size, void* d_ws, size_t ws_size,
                              hipStream_t stream) {
    const float* x    = (const float*)d_in[0];
    const int*   ei   = (const int*)d_in[1];   // [2, E]: row then col
    const int*   batch= (const int*)d_in[2];
    const float* meta = (const float*)d_in[3];
    const float* W1   = (const float*)d_in[4];
    const float* b1   = (const float*)d_in[5];
    const float* W2   = (const float*)d_in[6];
    const float* b2   = (const float*)d_in[7];
    const float* Wh1  = (const float*)d_in[8];
    const float* bh1  = (const float*)d_in[9];
    const float* Wh2  = (const float*)d_in[10];
    const float* bh2  = (const float*)d_in[11];
    float* out = (float*)d_out;

    const int N = N_NODES, E = N_EDGES, G = N_GRAPHS;
    const int* row = ei;
    const int* col = ei + E;

    // workspace layout (4-byte units), ~84.6 MB total (no aliasing).
    float*    ws      = (float*)d_ws;
    float*    dinv    = ws;                          // 512,000
    unsigned* packed  = (unsigned*)(ws + 512000);    // 9,004,032
    int*      srcs    = (int*)(packed + 9004032);    // 8,000,000
    unsigned* hsu     = (unsigned*)(srcs + 8000000); // 2,000,000 (fp8, 16B/node)
    unsigned* hs2u    = hsu + 2000000;               // 2,000,000 (fp8, 16B/node)
    float*    pooled  = (float*)(hs2u + 2000000);    // 131,072
    float*    cnt     = pooled + G * 16;             // 8,192
    int*      gcursor = (int*)(cnt + G);             // 1,024
    int*      goff    = gcursor + 1024;              // 1,024
    int*      rowptr  = goff + 1024;                 // 500,001

    dim3 blk(256);

    // ---- one-pass bucket build + CSR (+fused fp8 l1) ----
    k_init<<<(G * 17 + 255) / 256, blk, 0, stream>>>(pooled, gcursor);
    k_build<<<NTB2, dim3(1024), 0, stream>>>((const int4*)row, (const int4*)col,
                                             gcursor, packed, E);
    k_goff<<<1, dim3(1024), 0, stream>>>(gcursor, goff);
    k_csr<<<NBK, dim3(1024), 0, stream>>>(packed, goff, x, W1,
                                          srcs, rowptr, dinv, (uint4*)hsu, N);

    // ---- layer 1 aggregation (fp8 gather, 1 lane/node) ----
    k_pullA<<<(N + 255) / 256, blk, 0, stream>>>(rowptr, srcs, (const uint4*)hsu,
                                                 dinv, b1, W2, (uint4*)hs2u, N);

    // ---- layer 2 aggregation (fp8) + fused transform + fused pool ----
    int gP2 = (N * 2 + 255) / 256;
    k_pullB<<<gP2, blk, 0, stream>>>(rowptr, srcs, (const uint2*)hs2u, dinv,
                                     b2, batch, pooled, cnt, N);

    // ---- head ----
    k_head<<<(G + 255) / 256, blk, 0, stream>>>(pooled, cnt, meta, Wh1, bh1, Wh2, bh2, out, G);
}